// Round 14
// baseline (134.398 us; speedup 1.0000x reference)
//
#include <hip/hip_runtime.h>
#include <hip/hip_bf16.h>

// Problem constants
#define M_VIEWS 6
#define N_ROWS  2048
#define D_IN    1152
#define D_HID   128
#define D_K     64
#define TOT_ROWS (M_VIEWS * N_ROWS)   // 12288
// E is pre-scaled by sqrt((1/tau) * log2(e)) so E'.E' = (s/tau)*log2(e):
// pair-LSE softmax runs in exp2/log2 domain with no per-element muls.
#define SCALE_E 1.6986436f
#define LOG2E   1.4426950408889634f

typedef short bf16x8 __attribute__((ext_vector_type(8)));
typedef float f32x4  __attribute__((ext_vector_type(4)));

typedef __attribute__((address_space(1))) const void gvoid_t;
typedef __attribute__((address_space(3))) void svoid_t;

__device__ inline void async16(const void* g, void* l) {
    __builtin_amdgcn_global_load_lds((gvoid_t*)g, (svoid_t*)l, 16, 0, 0);
}

#if __has_builtin(__builtin_amdgcn_exp2f)
__device__ inline float fexp2(float x) { return __builtin_amdgcn_exp2f(x); }
#else
__device__ inline float fexp2(float x) { return exp2f(x); }
#endif
#if __has_builtin(__builtin_amdgcn_logf)
__device__ inline float flog2(float x) { return __builtin_amdgcn_logf(x); }
#else
__device__ inline float flog2(float x) { return log2f(x); }
#endif

// split f32 -> bf16 hi (x) + bf16 lo residual (y), returned by value
__device__ inline short2 splitf(float v) {
    __hip_bfloat16 hb = __float2bfloat16(v);
    float rem = v - __bfloat162float(hb);
    __hip_bfloat16 lb = __float2bfloat16(rem);
    short2 r;
    r.x = *reinterpret_cast<const short*>(&hb);
    r.y = *reinterpret_cast<const short*>(&lb);
    return r;
}

__device__ inline short bf16of(float v) {
    __hip_bfloat16 hb = __float2bfloat16(v);
    return *reinterpret_cast<const short*>(&hb);
}

// ---------------------------------------------------------------------------
// Kernel 0 (fused): blocks [0,288): W -> bf16 fragments (single term);
// blocks [288,352): U/V -> hi/lo split fragments (logits*LOG2E + E-B).
// ---------------------------------------------------------------------------
__global__ __launch_bounds__(64) void prep_kernel(
    const float* __restrict__ W,
    const float* __restrict__ U, const float* __restrict__ V,
    __hip_bfloat16* __restrict__ Whi,
    __hip_bfloat16* __restrict__ Pfhi, __hip_bfloat16* __restrict__ Pflo)
{
    const int lane = threadIdx.x;
    const int lg = lane >> 4, lr = lane & 15;

    if (blockIdx.x < 288) {
        const int s  = blockIdx.x >> 3;   // 0..35
        const int ct = blockIdx.x & 7;    // 0..7
        bf16x8 hi;
        #pragma unroll
        for (int i = 0; i < 8; ++i)
            hi[i] = bf16of(W[(size_t)(s * 32 + lg * 8 + i) * D_HID + ct * 16 + lr]);
        size_t off = ((size_t)(s * 8 + ct) * 64 + lane) * 8;
        *reinterpret_cast<bf16x8*>(Whi + off) = hi;
    } else {
        const int blk = blockIdx.x - 288;  // 0..63
        const int mat = blk >> 5, f = blk & 31;
        const float* P = mat ? V : U;
        bf16x8 hi, lo;
        #pragma unroll
        for (int i = 0; i < 8; ++i) {
            float w;
            if (f < 16) {
                int s = f >> 2, ct = f & 3;
                w = P[(size_t)(s * 32 + lg * 8 + i) * D_K + ct * 16 + lr] * LOG2E;
            } else {
                int g = f - 16, s2 = g >> 3, ct2 = g & 7;
                w = P[(size_t)(ct2 * 16 + lr) * D_K + s2 * 32 + lg * 8 + i];
            }
            short2 hl = splitf(w);
            hi[i] = hl.x; lo[i] = hl.y;
        }
        size_t off = ((size_t)(mat * 32 + f) * 64 + lane) * 8;
        *reinterpret_cast<bf16x8*>(Pfhi + off) = hi;
        *reinterpret_cast<bf16x8*>(Pflo + off) = lo;
    }
}

// ---------------------------------------------------------------------------
// Kernel 1+2 FUSED, 8 waves: x = x_all@W + b (bf16 MFMA, 8-way K-split:
// waves 0-3 take 5 k-steps, waves 4-7 take 4), tree-reduced through LDS;
// then retrieve: waves 0/1 do logits+softmax (one mat each), all 8 waves
// split the E-GEMM (2 ct2 each). x never touches global memory.
// ---------------------------------------------------------------------------
__global__ __launch_bounds__(512) void xretrieve_kernel(
    const float* __restrict__ xall,
    const __hip_bfloat16* __restrict__ Whi,
    const float* __restrict__ bias,
    const __hip_bfloat16* __restrict__ Pfhi,
    const __hip_bfloat16* __restrict__ Pflo,
    __hip_bfloat16* __restrict__ E)
{
    __shared__ __align__(16) char smem[32768 + 8448 + 9216];   // 50.4 KB
    f32x4* red = reinterpret_cast<f32x4*>(smem);               // 4 bufs x 512
    float* xs  = reinterpret_cast<float*>(smem + 32768);       // 16 x 132
    float* alb = reinterpret_cast<float*>(smem + 32768 + 8448);// 2 x 16 x 72

    const int wave = threadIdx.x >> 6, lane = threadIdx.x & 63;
    const int lg = lane >> 4, lr = lane & 15;
    const int row0 = blockIdx.x * 16;

    // ---- phase 1: xgemm (single-term bf16), 8-way K-split ----
    const int nst = (wave < 4) ? 5 : 4;
    const int st0 = (wave < 4) ? wave * 5 : 20 + (wave - 4) * 4;
    const float* ap = xall + (size_t)(row0 + lr) * D_IN + st0 * 32;

    f32x4 acc[8];
    #pragma unroll
    for (int ct = 0; ct < 8; ++ct) acc[ct] = {0.f, 0.f, 0.f, 0.f};

    const bf16x8* whb = reinterpret_cast<const bf16x8*>(Whi) + lane;
    for (int s = 0; s < nst; ++s) {
        const int gs = st0 + s;
        const float* a8 = ap + s * 32 + lg * 8;
        float4 va = *reinterpret_cast<const float4*>(a8);
        float4 vb = *reinterpret_cast<const float4*>(a8 + 4);
        bf16x8 ah;
        ah[0] = bf16of(va.x); ah[1] = bf16of(va.y);
        ah[2] = bf16of(va.z); ah[3] = bf16of(va.w);
        ah[4] = bf16of(vb.x); ah[5] = bf16of(vb.y);
        ah[6] = bf16of(vb.z); ah[7] = bf16of(vb.w);
        #pragma unroll
        for (int ct = 0; ct < 8; ++ct) {
            bf16x8 wh = whb[(size_t)(gs * 8 + ct) * 64];
            acc[ct] = __builtin_amdgcn_mfma_f32_16x16x32_bf16(ah, wh, acc[ct], 0, 0, 0);
        }
    }

    // tree reduction: 8 -> 4 -> 1
    if (wave >= 4) {
        #pragma unroll
        for (int ct = 0; ct < 8; ++ct)
            red[(wave - 4) * 512 + ct * 64 + lane] = acc[ct];
    }
    __syncthreads();
    if (wave < 4) {
        #pragma unroll
        for (int ct = 0; ct < 8; ++ct)
            acc[ct] += red[wave * 512 + ct * 64 + lane];
    }
    __syncthreads();   // WAR: red re-written below
    if (wave >= 1 && wave < 4) {
        #pragma unroll
        for (int ct = 0; ct < 8; ++ct)
            red[(wave - 1) * 512 + ct * 64 + lane] = acc[ct];
    }
    __syncthreads();
    if (wave == 0) {
        #pragma unroll
        for (int ct = 0; ct < 8; ++ct) {
            f32x4 a = acc[ct];
            a += red[ct * 64 + lane];
            a += red[512 + ct * 64 + lane];
            a += red[1024 + ct * 64 + lane];
            float bj = bias[ct * 16 + lr];
            #pragma unroll
            for (int j = 0; j < 4; ++j)
                xs[(lg * 4 + j) * 132 + ct * 16 + lr] = a[j] + bj;
        }
    }
    __syncthreads();   // xs visible

    // ---- phase 2a: logits + softmax (waves 0,1 = mats U,V) ----
    if (wave < 2) {
        const int mat = wave;
        bf16x8 xh[4], xl[4];
        #pragma unroll
        for (int s = 0; s < 4; ++s) {
            const float* xp = xs + lr * 132 + s * 32 + lg * 8;
            float4 va = *reinterpret_cast<const float4*>(xp);
            float4 vb = *reinterpret_cast<const float4*>(xp + 4);
            float v[8] = {va.x, va.y, va.z, va.w, vb.x, vb.y, vb.z, vb.w};
            #pragma unroll
            for (int i = 0; i < 8; ++i) {
                short2 hl = splitf(v[i]);
                xh[s][i] = hl.x; xl[s][i] = hl.y;
            }
        }

        const bf16x8* bh = reinterpret_cast<const bf16x8*>(Pfhi) + (size_t)mat * 32 * 64 + lane;
        const bf16x8* bl = reinterpret_cast<const bf16x8*>(Pflo) + (size_t)mat * 32 * 64 + lane;

        f32x4 lacc[4];
        #pragma unroll
        for (int ct = 0; ct < 4; ++ct) lacc[ct] = {0.f, 0.f, 0.f, 0.f};
        #pragma unroll
        for (int ct = 0; ct < 4; ++ct) {
            #pragma unroll
            for (int s = 0; s < 4; ++s) {
                bf16x8 wh = bh[(s * 4 + ct) * 64];
                bf16x8 wl = bl[(s * 4 + ct) * 64];
                lacc[ct] = __builtin_amdgcn_mfma_f32_16x16x32_bf16(xh[s], wh, lacc[ct], 0, 0, 0);
                lacc[ct] = __builtin_amdgcn_mfma_f32_16x16x32_bf16(xl[s], wh, lacc[ct], 0, 0, 0);
                lacc[ct] = __builtin_amdgcn_mfma_f32_16x16x32_bf16(xh[s], wl, lacc[ct], 0, 0, 0);
            }
        }

        float* al = alb + mat * (16 * 72);
        #pragma unroll
        for (int j = 0; j < 4; ++j) {
            float l0 = lacc[0][j], l1 = lacc[1][j], l2 = lacc[2][j], l3 = lacc[3][j];
            float mx = fmaxf(fmaxf(l0, l1), fmaxf(l2, l3));
            #pragma unroll
            for (int s = 1; s < 16; s <<= 1) mx = fmaxf(mx, __shfl_xor(mx, s));
            float p0 = fexp2(l0 - mx), p1 = fexp2(l1 - mx);
            float p2 = fexp2(l2 - mx), p3 = fexp2(l3 - mx);
            float sm = p0 + p1 + p2 + p3;
            #pragma unroll
            for (int s = 1; s < 16; s <<= 1) sm += __shfl_xor(sm, s);
            float inv = 1.0f / sm;
            float* ar = al + (lg * 4 + j) * 72;
            ar[lr]      = p0 * inv;
            ar[16 + lr] = p1 * inv;
            ar[32 + lr] = p2 * inv;
            ar[48 + lr] = p3 * inv;
        }
    }
    __syncthreads();   // al visible (both mats)

    // ---- phase 2b: E-GEMM split over all 8 waves (mat = wave&1, 2 ct2) ----
    {
        const int mat2 = wave & 1;
        const int cp   = wave >> 1;       // 0..3 -> ct2 in {2cp, 2cp+1}
        const float* al = alb + mat2 * (16 * 72);
        const bf16x8* bh = reinterpret_cast<const bf16x8*>(Pfhi) + (size_t)mat2 * 32 * 64 + lane;
        const bf16x8* bl = reinterpret_cast<const bf16x8*>(Pflo) + (size_t)mat2 * 32 * 64 + lane;

        bf16x8 aah[2], aal[2];
        #pragma unroll
        for (int s2 = 0; s2 < 2; ++s2) {
            const float* ap2 = al + lr * 72 + s2 * 32 + lg * 8;
            float4 va = *reinterpret_cast<const float4*>(ap2);
            float4 vb = *reinterpret_cast<const float4*>(ap2 + 4);
            float v[8] = {va.x, va.y, va.z, va.w, vb.x, vb.y, vb.z, vb.w};
            #pragma unroll
            for (int i = 0; i < 8; ++i) {
                short2 hl = splitf(v[i]);
                aah[s2][i] = hl.x; aal[s2][i] = hl.y;
            }
        }

        __hip_bfloat16* Er = E + ((size_t)mat2 * TOT_ROWS + row0) * D_HID;
        #pragma unroll
        for (int q = 0; q < 2; ++q) {
            const int ct2 = cp * 2 + q;
            f32x4 eacc = {0.f, 0.f, 0.f, 0.f};
            #pragma unroll
            for (int s2 = 0; s2 < 2; ++s2) {
                bf16x8 wh = bh[(16 + s2 * 8 + ct2) * 64];
                bf16x8 wl = bl[(16 + s2 * 8 + ct2) * 64];
                eacc = __builtin_amdgcn_mfma_f32_16x16x32_bf16(aah[s2], wh, eacc, 0, 0, 0);
                eacc = __builtin_amdgcn_mfma_f32_16x16x32_bf16(aal[s2], wh, eacc, 0, 0, 0);
                eacc = __builtin_amdgcn_mfma_f32_16x16x32_bf16(aah[s2], wl, eacc, 0, 0, 0);
            }
            #pragma unroll
            for (int j = 0; j < 4; ++j)
                Er[(size_t)(lg * 4 + j) * D_HID + ct2 * 16 + lr] =
                    __float2bfloat16(eacc[j] * SCALE_E);
        }
    }
}

// ---------------------------------------------------------------------------
// Kernel 3: pair LSE, K-SPLIT (R9 version — measured best, 102.5 us).
// 960 blocks x 512 threads (8 waves, rf=2), per-tile-max online LSE.
// ---------------------------------------------------------------------------
__global__ __launch_bounds__(512) void pair_lse_kernel(
    const __hip_bfloat16* __restrict__ E,  // [2][6][2048][128], pre-scaled
    float* __restrict__ partial)           // [60][2048][2 halves][3]
{
    __shared__ __align__(16) unsigned char kbuf[2 * 16384];

    const int bid    = blockIdx.x;
    const int linear = (bid & 7) * 120 + (bid >> 3);  // 960 = 8 XCD x 120
    const int half = linear & 1;
    const int qt   = (linear >> 1) & 7;
    const int job  = linear >> 4;        // 0..59
    const int mat = job / 30;
    const int pr  = job % 30;
    const int m   = pr / 5;
    int k = pr % 5; k += (k >= m);

    const __hip_bfloat16* Qm = E + ((size_t)(mat * M_VIEWS + m)) * N_ROWS * D_HID;
    const __hip_bfloat16* Kk = E + ((size_t)(mat * M_VIEWS + k)) * N_ROWS * D_HID;

    const int tid  = threadIdx.x;
    const int wave = tid >> 6, lane = tid & 63;
    const int lr = lane & 15, lg = lane >> 4;

    const int qrow0 = qt * 256 + wave * 32;

    bf16x8 afrag[2][4];
    #pragma unroll
    for (int rf = 0; rf < 2; ++rf) {
        const __hip_bfloat16* qp = Qm + (size_t)(qrow0 + rf * 16 + lr) * D_HID;
        #pragma unroll
        for (int s = 0; s < 4; ++s)
            afrag[rf][s] = *reinterpret_cast<const bf16x8*>(qp + s * 32 + lg * 8);
    }

    float mrun[2][4], lrun[2][4], pos[2][4];
    #pragma unroll
    for (int rf = 0; rf < 2; ++rf)
        #pragma unroll
        for (int j = 0; j < 4; ++j) {
            mrun[rf][j] = -1e30f; lrun[rf][j] = 0.f; pos[rf][j] = 0.f;
        }

    const int ptdiag = qt * 4 + (wave >> 1);
    const int ctd0   = (wave & 1) * 2;
    const int pt0    = half * 16;

    #define STAGE(pt, b)                                                        \
        {                                                                       \
            const char* base = (const char*)Kk + (size_t)(pt) * 16384;          \
            _Pragma("unroll")                                                   \
            for (int i = 0; i < 2; ++i) {                                       \
                int f = wave * 2 + i;                                           \
                int ct_ = f >> 2, s_ = f & 3;                                   \
                async16(base + (ct_ * 16 + lr) * 256 + s_ * 64 + lg * 16,       \
                        kbuf + (b) * 16384 + f * 1024);                         \
            }                                                                   \
        }

    STAGE(pt0, 0);
    __syncthreads();

    const unsigned char* kb0 = kbuf + lane * 16;
    for (int t = 0; t < 16; ++t) {
        const int pt = pt0 + t;
        if (t < 15) STAGE(pt + 1, (t + 1) & 1);

        const unsigned char* kb = kb0 + (t & 1) * 16384;
        f32x4 acc[2][4];
        #pragma unroll
        for (int rf = 0; rf < 2; ++rf)
            #pragma unroll
            for (int ct = 0; ct < 4; ++ct) acc[rf][ct] = {0.f, 0.f, 0.f, 0.f};

        #pragma unroll
        for (int ct = 0; ct < 4; ++ct) {
            #pragma unroll
            for (int s = 0; s < 4; ++s) {
                bf16x8 bf = *reinterpret_cast<const bf16x8*>(kb + (ct * 4 + s) * 1024);
                acc[0][ct] = __builtin_amdgcn_mfma_f32_16x16x32_bf16(afrag[0][s], bf, acc[0][ct], 0, 0, 0);
                acc[1][ct] = __builtin_amdgcn_mfma_f32_16x16x32_bf16(afrag[1][s], bf, acc[1][ct], 0, 0, 0);
            }
        }

        const bool dtile = (pt == ptdiag);
        #pragma unroll
        for (int rf = 0; rf < 2; ++rf) {
            #pragma unroll
            for (int j = 0; j < 4; ++j) {
                float v0 = acc[rf][0][j], v1 = acc[rf][1][j];
                float v2 = acc[rf][2][j], v3 = acc[rf][3][j];
                if (dtile) {
                    const int cd = ctd0 + rf;     // wave-uniform
                    const bool dl = (lr == lg * 4 + j);
                    float vd = (cd == 0) ? v0 : (cd == 1) ? v1 : (cd == 2) ? v2 : v3;
                    if (dl) {
                        pos[rf][j] = vd;
                        float nv = -INFINITY;
                        if      (cd == 0) v0 = nv;
                        else if (cd == 1) v1 = nv;
                        else if (cd == 2) v2 = nv;
                        else              v3 = nv;
                    }
                }
                float tmax = fmaxf(fmaxf(v0, v1), fmaxf(v2, v3));
                float nm = fmaxf(mrun[rf][j], tmax);
                float ps = fexp2(v0 - nm) + fexp2(v1 - nm)
                         + fexp2(v2 - nm) + fexp2(v3 - nm);
                lrun[rf][j] = lrun[rf][j] * fexp2(mrun[rf][j] - nm) + ps;
                mrun[rf][j] = nm;
            }
        }
        __syncthreads();
    }

    #pragma unroll
    for (int rf = 0; rf < 2; ++rf) {
        #pragma unroll
        for (int j = 0; j < 4; ++j) {
            float Mv = mrun[rf][j], Lv = lrun[rf][j];
            #pragma unroll
            for (int s = 1; s < 16; s <<= 1) {
                float Mo = __shfl_xor(Mv, s);
                float Lo = __shfl_xor(Lv, s);
                float nm = fmaxf(Mv, Mo);
                Lv = Lv * fexp2(Mv - nm) + Lo * fexp2(Mo - nm);
                Mv = nm;
            }
            float P = pos[rf][j];
            #pragma unroll
            for (int s = 1; s < 16; s <<= 1) P += __shfl_xor(P, s);
            if (lr == 0) {
                const int row = qrow0 + rf * 16 + lg * 4 + j;
                float* dst = partial + (((size_t)job * N_ROWS + row) * 2 + half) * 3;
                dst[0] = Mv; dst[1] = Lv; dst[2] = P;
            }
        }
    }
}

// ---------------------------------------------------------------------------
// Kernel 4: merge the two K-halves per row, sum (lse - pos) into out.
// ---------------------------------------------------------------------------
__global__ __launch_bounds__(256) void merge_kernel(
    const float* __restrict__ partial, float* __restrict__ out, float scale)
{
    __shared__ float wsum[4];
    const int r = blockIdx.x * 256 + threadIdx.x;   // 0 .. 60*2048-1
    const float* p = partial + (size_t)r * 6;
    float m0 = p[0], l0 = p[1], p0 = p[2];
    float m1 = p[3], l1 = p[4], p1 = p[5];
    float ms = fmaxf(m0, m1);
    float L  = l0 * fexp2(m0 - ms) + l1 * fexp2(m1 - ms);
    float c  = (ms + flog2(L)) - (p0 + p1);

    #pragma unroll
    for (int s = 1; s < 64; s <<= 1) c += __shfl_xor(c, s);
    const int wave = threadIdx.x >> 6, lane = threadIdx.x & 63;
    if (lane == 0) wsum[wave] = c;
    __syncthreads();
    if (threadIdx.x == 0)
        atomicAdd(out, (wsum[0] + wsum[1] + wsum[2] + wsum[3]) * scale);
}

// ---------------------------------------------------------------------------
extern "C" void kernel_launch(void* const* d_in, const int* in_sizes, int n_in,
                              void* d_out, int out_size, void* d_ws, size_t ws_size,
                              hipStream_t stream) {
    const float* xall = (const float*)d_in[0];
    const float* W    = (const float*)d_in[1];
    const float* b    = (const float*)d_in[2];
    const float* U    = (const float*)d_in[3];
    const float* V    = (const float*)d_in[4];
    float* out = (float*)d_out;

    char* ws = (char*)d_ws;
    __hip_bfloat16* E   = (__hip_bfloat16*)ws;                 // 6.29 MB
    __hip_bfloat16* Whi = E + 2 * (size_t)TOT_ROWS * D_HID;    // 294,912 B
    __hip_bfloat16* Pfhi = Whi + 36 * 8 * 64 * 8;              // 64 KB
    __hip_bfloat16* Pflo = Pfhi + 2 * 32 * 64 * 8;             // 64 KB
    float* partial = (float*)(Pflo + 2 * 32 * 64 * 8);         // 2.95 MB

    (void)hipMemsetAsync(d_out, 0, sizeof(float), stream);

    prep_kernel<<<352, 64, 0, stream>>>(W, U, V, Whi, Pfhi, Pflo);
    xretrieve_kernel<<<TOT_ROWS / 16, 512, 0, stream>>>(xall, Whi, b, Pfhi, Pflo, E);

    pair_lse_kernel<<<960, 512, 0, stream>>>(E, partial);

    const float scale = 0.6931471805599453f / (2048.0f * 60.0f);
    merge_kernel<<<60 * 2048 / 256, 256, 0, stream>>>(partial, out, scale);
}

// Round 15
// 123.922 us; speedup vs baseline: 1.0845x; 1.0845x over previous
//
#include <hip/hip_runtime.h>
#include <hip/hip_bf16.h>

// Problem constants
#define M_VIEWS 6
#define N_ROWS  2048
#define D_IN    1152
#define D_HID   128
#define D_K     64
#define TOT_ROWS (M_VIEWS * N_ROWS)   // 12288
// E is pre-scaled by sqrt((1/tau) * log2(e)) so E'.E' = (s/tau)*log2(e):
// pair-LSE softmax runs in exp2/log2 domain with no per-element muls.
#define SCALE_E 1.6986436f
#define LOG2E   1.4426950408889634f

typedef short bf16x8 __attribute__((ext_vector_type(8)));
typedef float f32x4  __attribute__((ext_vector_type(4)));

typedef __attribute__((address_space(1))) const void gvoid_t;
typedef __attribute__((address_space(3))) void svoid_t;

__device__ inline void async16(const void* g, void* l) {
    __builtin_amdgcn_global_load_lds((gvoid_t*)g, (svoid_t*)l, 16, 0, 0);
}

#if __has_builtin(__builtin_amdgcn_exp2f)
__device__ inline float fexp2(float x) { return __builtin_amdgcn_exp2f(x); }
#else
__device__ inline float fexp2(float x) { return exp2f(x); }
#endif
#if __has_builtin(__builtin_amdgcn_logf)
__device__ inline float flog2(float x) { return __builtin_amdgcn_logf(x); }
#else
__device__ inline float flog2(float x) { return log2f(x); }
#endif

// split f32 -> bf16 hi (x) + bf16 lo residual (y), returned by value
__device__ inline short2 splitf(float v) {
    __hip_bfloat16 hb = __float2bfloat16(v);
    float rem = v - __bfloat162float(hb);
    __hip_bfloat16 lb = __float2bfloat16(rem);
    short2 r;
    r.x = *reinterpret_cast<const short*>(&hb);
    r.y = *reinterpret_cast<const short*>(&lb);
    return r;
}

__device__ inline short bf16of(float v) {
    __hip_bfloat16 hb = __float2bfloat16(v);
    return *reinterpret_cast<const short*>(&hb);
}

// ---------------------------------------------------------------------------
// Kernel 0 (fused): blocks [0,288): W -> bf16 fragments (single term);
// blocks [288,352): U/V -> hi/lo split fragments (logits*LOG2E + E-B).
// ---------------------------------------------------------------------------
__global__ __launch_bounds__(64) void prep_kernel(
    const float* __restrict__ W,
    const float* __restrict__ U, const float* __restrict__ V,
    __hip_bfloat16* __restrict__ Whi,
    __hip_bfloat16* __restrict__ Pfhi, __hip_bfloat16* __restrict__ Pflo)
{
    const int lane = threadIdx.x;
    const int lg = lane >> 4, lr = lane & 15;

    if (blockIdx.x < 288) {
        const int s  = blockIdx.x >> 3;   // 0..35
        const int ct = blockIdx.x & 7;    // 0..7
        bf16x8 hi;
        #pragma unroll
        for (int i = 0; i < 8; ++i)
            hi[i] = bf16of(W[(size_t)(s * 32 + lg * 8 + i) * D_HID + ct * 16 + lr]);
        size_t off = ((size_t)(s * 8 + ct) * 64 + lane) * 8;
        *reinterpret_cast<bf16x8*>(Whi + off) = hi;
    } else {
        const int blk = blockIdx.x - 288;  // 0..63
        const int mat = blk >> 5, f = blk & 31;
        const float* P = mat ? V : U;
        bf16x8 hi, lo;
        #pragma unroll
        for (int i = 0; i < 8; ++i) {
            float w;
            if (f < 16) {
                int s = f >> 2, ct = f & 3;
                w = P[(size_t)(s * 32 + lg * 8 + i) * D_K + ct * 16 + lr] * LOG2E;
            } else {
                int g = f - 16, s2 = g >> 3, ct2 = g & 7;
                w = P[(size_t)(ct2 * 16 + lr) * D_K + s2 * 32 + lg * 8 + i];
            }
            short2 hl = splitf(w);
            hi[i] = hl.x; lo[i] = hl.y;
        }
        size_t off = ((size_t)(mat * 32 + f) * 64 + lane) * 8;
        *reinterpret_cast<bf16x8*>(Pfhi + off) = hi;
        *reinterpret_cast<bf16x8*>(Pflo + off) = lo;
    }
}

// ---------------------------------------------------------------------------
// Kernel 1+2 FUSED (R13 geometry): x = x_all@W + b (bf16 MFMA, K-split over
// 4 waves), then retrieve — waves 0/1 do logits+softmax (one mat each), all
// 4 waves split the E-GEMM (mat = wave&1, 4 ct2 each). x never hits global.
// ---------------------------------------------------------------------------
__global__ __launch_bounds__(256) void xretrieve_kernel(
    const float* __restrict__ xall,
    const __hip_bfloat16* __restrict__ Whi,
    const float* __restrict__ bias,
    const __hip_bfloat16* __restrict__ Pfhi,
    const __hip_bfloat16* __restrict__ Pflo,
    __hip_bfloat16* __restrict__ E)
{
    __shared__ __align__(16) char smem[24576];   // red (24576) -> xs+al
    f32x4* red = reinterpret_cast<f32x4*>(smem);           // 3*512 f32x4
    float* xs  = reinterpret_cast<float*>(smem);           // 16*132 f32 = 8448B
    float* alb = reinterpret_cast<float*>(smem + 8448);    // 2*16*72 f32 = 9216B

    const int wave = threadIdx.x >> 6, lane = threadIdx.x & 63;
    const int lg = lane >> 4, lr = lane & 15;
    const int row0 = blockIdx.x * 16;

    // ---- phase 1: xgemm (single-term bf16) ----
    const float* ap = xall + (size_t)(row0 + lr) * D_IN + wave * 288;
    f32x4 acc[8];
    #pragma unroll
    for (int ct = 0; ct < 8; ++ct) acc[ct] = {0.f, 0.f, 0.f, 0.f};

    const bf16x8* whb = reinterpret_cast<const bf16x8*>(Whi) + lane;
    for (int s = 0; s < 9; ++s) {
        const int gs = wave * 9 + s;
        const float* a8 = ap + s * 32 + lg * 8;
        float4 va = *reinterpret_cast<const float4*>(a8);
        float4 vb = *reinterpret_cast<const float4*>(a8 + 4);
        bf16x8 ah;
        ah[0] = bf16of(va.x); ah[1] = bf16of(va.y);
        ah[2] = bf16of(va.z); ah[3] = bf16of(va.w);
        ah[4] = bf16of(vb.x); ah[5] = bf16of(vb.y);
        ah[6] = bf16of(vb.z); ah[7] = bf16of(vb.w);
        #pragma unroll
        for (int ct = 0; ct < 8; ++ct) {
            bf16x8 wh = whb[(size_t)(gs * 8 + ct) * 64];
            acc[ct] = __builtin_amdgcn_mfma_f32_16x16x32_bf16(ah, wh, acc[ct], 0, 0, 0);
        }
    }

    if (wave > 0) {
        #pragma unroll
        for (int ct = 0; ct < 8; ++ct)
            red[(wave - 1) * 512 + ct * 64 + lane] = acc[ct];
    }
    __syncthreads();
    if (wave == 0) {
        f32x4 xv[8];
        #pragma unroll
        for (int ct = 0; ct < 8; ++ct) {
            f32x4 a = acc[ct];
            a += red[ct * 64 + lane];
            a += red[512 + ct * 64 + lane];
            a += red[1024 + ct * 64 + lane];
            float bj = bias[ct * 16 + lr];
            #pragma unroll
            for (int j = 0; j < 4; ++j) xv[ct][j] = a[j] + bj;
        }
        __syncthreads();   // red reads done before overwrite with xs
        #pragma unroll
        for (int ct = 0; ct < 8; ++ct)
            #pragma unroll
            for (int j = 0; j < 4; ++j)
                xs[(lg * 4 + j) * 132 + ct * 16 + lr] = xv[ct][j];
    } else {
        __syncthreads();   // matching barrier
    }
    __syncthreads();       // xs visible to all

    // ---- phase 2a: logits + softmax (waves 0,1 = mats U,V) ----
    if (wave < 2) {
        const int mat = wave;
        bf16x8 xh[4], xl[4];
        #pragma unroll
        for (int s = 0; s < 4; ++s) {
            const float* xp = xs + lr * 132 + s * 32 + lg * 8;
            float4 va = *reinterpret_cast<const float4*>(xp);
            float4 vb = *reinterpret_cast<const float4*>(xp + 4);
            float v[8] = {va.x, va.y, va.z, va.w, vb.x, vb.y, vb.z, vb.w};
            #pragma unroll
            for (int i = 0; i < 8; ++i) {
                short2 hl = splitf(v[i]);
                xh[s][i] = hl.x; xl[s][i] = hl.y;
            }
        }

        const bf16x8* bh = reinterpret_cast<const bf16x8*>(Pfhi) + (size_t)mat * 32 * 64 + lane;
        const bf16x8* bl = reinterpret_cast<const bf16x8*>(Pflo) + (size_t)mat * 32 * 64 + lane;

        f32x4 lacc[4];
        #pragma unroll
        for (int ct = 0; ct < 4; ++ct) lacc[ct] = {0.f, 0.f, 0.f, 0.f};
        #pragma unroll
        for (int ct = 0; ct < 4; ++ct) {
            #pragma unroll
            for (int s = 0; s < 4; ++s) {
                bf16x8 wh = bh[(s * 4 + ct) * 64];
                bf16x8 wl = bl[(s * 4 + ct) * 64];
                lacc[ct] = __builtin_amdgcn_mfma_f32_16x16x32_bf16(xh[s], wh, lacc[ct], 0, 0, 0);
                lacc[ct] = __builtin_amdgcn_mfma_f32_16x16x32_bf16(xl[s], wh, lacc[ct], 0, 0, 0);
                lacc[ct] = __builtin_amdgcn_mfma_f32_16x16x32_bf16(xh[s], wl, lacc[ct], 0, 0, 0);
            }
        }

        float* al = alb + mat * (16 * 72);
        #pragma unroll
        for (int j = 0; j < 4; ++j) {
            float l0 = lacc[0][j], l1 = lacc[1][j], l2 = lacc[2][j], l3 = lacc[3][j];
            float mx = fmaxf(fmaxf(l0, l1), fmaxf(l2, l3));
            #pragma unroll
            for (int s = 1; s < 16; s <<= 1) mx = fmaxf(mx, __shfl_xor(mx, s));
            float p0 = fexp2(l0 - mx), p1 = fexp2(l1 - mx);
            float p2 = fexp2(l2 - mx), p3 = fexp2(l3 - mx);
            float sm = p0 + p1 + p2 + p3;
            #pragma unroll
            for (int s = 1; s < 16; s <<= 1) sm += __shfl_xor(sm, s);
            float inv = 1.0f / sm;
            float* ar = al + (lg * 4 + j) * 72;
            ar[lr]      = p0 * inv;
            ar[16 + lr] = p1 * inv;
            ar[32 + lr] = p2 * inv;
            ar[48 + lr] = p3 * inv;
        }
    }
    __syncthreads();   // al visible (both mats)

    // ---- phase 2b: E-GEMM split over all 4 waves (mat = wave&1, 4 ct2) ----
    {
        const int mat2 = wave & 1;
        const int cp   = wave >> 1;       // 0..1 -> ct2 in [4cp, 4cp+4)
        const float* al = alb + mat2 * (16 * 72);
        const bf16x8* bh = reinterpret_cast<const bf16x8*>(Pfhi) + (size_t)mat2 * 32 * 64 + lane;
        const bf16x8* bl = reinterpret_cast<const bf16x8*>(Pflo) + (size_t)mat2 * 32 * 64 + lane;

        bf16x8 aah[2], aal[2];
        #pragma unroll
        for (int s2 = 0; s2 < 2; ++s2) {
            const float* ap2 = al + lr * 72 + s2 * 32 + lg * 8;
            float4 va = *reinterpret_cast<const float4*>(ap2);
            float4 vb = *reinterpret_cast<const float4*>(ap2 + 4);
            float v[8] = {va.x, va.y, va.z, va.w, vb.x, vb.y, vb.z, vb.w};
            #pragma unroll
            for (int i = 0; i < 8; ++i) {
                short2 hl = splitf(v[i]);
                aah[s2][i] = hl.x; aal[s2][i] = hl.y;
            }
        }

        __hip_bfloat16* Er = E + ((size_t)mat2 * TOT_ROWS + row0) * D_HID;
        #pragma unroll
        for (int q = 0; q < 4; ++q) {
            const int ct2 = cp * 4 + q;
            f32x4 eacc = {0.f, 0.f, 0.f, 0.f};
            #pragma unroll
            for (int s2 = 0; s2 < 2; ++s2) {
                bf16x8 wh = bh[(16 + s2 * 8 + ct2) * 64];
                bf16x8 wl = bl[(16 + s2 * 8 + ct2) * 64];
                eacc = __builtin_amdgcn_mfma_f32_16x16x32_bf16(aah[s2], wh, eacc, 0, 0, 0);
                eacc = __builtin_amdgcn_mfma_f32_16x16x32_bf16(aal[s2], wh, eacc, 0, 0, 0);
                eacc = __builtin_amdgcn_mfma_f32_16x16x32_bf16(aah[s2], wl, eacc, 0, 0, 0);
            }
            #pragma unroll
            for (int j = 0; j < 4; ++j)
                Er[(size_t)(lg * 4 + j) * D_HID + ct2 * 16 + lr] =
                    __float2bfloat16(eacc[j] * SCALE_E);
        }
    }
}

// ---------------------------------------------------------------------------
// Kernel 3: pair LSE (R6 non-split version — 480 blocks, 32 p-tiles,
// in-kernel atomic finish; measured 103.5 us, merge kernel eliminated).
// 8 waves x 32 rows (rf=2), per-tile-max online LSE in exp2 domain.
// ---------------------------------------------------------------------------
__global__ __launch_bounds__(512) void pair_lse_kernel(
    const __hip_bfloat16* __restrict__ E,  // [2][6][2048][128], pre-scaled
    float* __restrict__ out, float scale)
{
    __shared__ __align__(16) unsigned char kbuf[2 * 16384];
    __shared__ float bsum[8];

    const int bid    = blockIdx.x;
    const int linear = (bid & 7) * 60 + (bid >> 3);   // 480 = 8 XCD x 60
    const int qt  = linear & 7;          // 0..7
    const int job = linear >> 3;         // 0..59
    const int mat = job / 30;
    const int pr  = job % 30;
    const int m   = pr / 5;
    int k = pr % 5; k += (k >= m);

    const __hip_bfloat16* Qm = E + ((size_t)(mat * M_VIEWS + m)) * N_ROWS * D_HID;
    const __hip_bfloat16* Kk = E + ((size_t)(mat * M_VIEWS + k)) * N_ROWS * D_HID;

    const int tid  = threadIdx.x;
    const int wave = tid >> 6, lane = tid & 63;
    const int lr = lane & 15, lg = lane >> 4;

    const int qrow0 = qt * 256 + wave * 32;

    bf16x8 afrag[2][4];
    #pragma unroll
    for (int rf = 0; rf < 2; ++rf) {
        const __hip_bfloat16* qp = Qm + (size_t)(qrow0 + rf * 16 + lr) * D_HID;
        #pragma unroll
        for (int s = 0; s < 4; ++s)
            afrag[rf][s] = *reinterpret_cast<const bf16x8*>(qp + s * 32 + lg * 8);
    }

    float mrun[2][4], lrun[2][4], pos[2][4];
    #pragma unroll
    for (int rf = 0; rf < 2; ++rf)
        #pragma unroll
        for (int j = 0; j < 4; ++j) {
            mrun[rf][j] = -1e30f; lrun[rf][j] = 0.f; pos[rf][j] = 0.f;
        }

    const int ptdiag = qt * 4 + (wave >> 1);
    const int ctd0   = (wave & 1) * 2;

    #define STAGE(pt, b)                                                        \
        {                                                                       \
            const char* base = (const char*)Kk + (size_t)(pt) * 16384;          \
            _Pragma("unroll")                                                   \
            for (int i = 0; i < 2; ++i) {                                       \
                int f = wave * 2 + i;                                           \
                int ct_ = f >> 2, s_ = f & 3;                                   \
                async16(base + (ct_ * 16 + lr) * 256 + s_ * 64 + lg * 16,       \
                        kbuf + (b) * 16384 + f * 1024);                         \
            }                                                                   \
        }

    STAGE(0, 0);
    __syncthreads();

    const unsigned char* kb0 = kbuf + lane * 16;
    int buf = 0;
    for (int pt = 0; pt < 32; ++pt) {
        if (pt < 31) STAGE(pt + 1, buf ^ 1);

        const unsigned char* kb = kb0 + buf * 16384;
        f32x4 acc[2][4];
        #pragma unroll
        for (int rf = 0; rf < 2; ++rf)
            #pragma unroll
            for (int ct = 0; ct < 4; ++ct) acc[rf][ct] = {0.f, 0.f, 0.f, 0.f};

        #pragma unroll
        for (int ct = 0; ct < 4; ++ct) {
            #pragma unroll
            for (int s = 0; s < 4; ++s) {
                bf16x8 bf = *reinterpret_cast<const bf16x8*>(kb + (ct * 4 + s) * 1024);
                acc[0][ct] = __builtin_amdgcn_mfma_f32_16x16x32_bf16(afrag[0][s], bf, acc[0][ct], 0, 0, 0);
                acc[1][ct] = __builtin_amdgcn_mfma_f32_16x16x32_bf16(afrag[1][s], bf, acc[1][ct], 0, 0, 0);
            }
        }

        const bool dtile = (pt == ptdiag);
        #pragma unroll
        for (int rf = 0; rf < 2; ++rf) {
            #pragma unroll
            for (int j = 0; j < 4; ++j) {
                float v0 = acc[rf][0][j], v1 = acc[rf][1][j];
                float v2 = acc[rf][2][j], v3 = acc[rf][3][j];
                if (dtile) {
                    const int cd = ctd0 + rf;     // wave-uniform
                    const bool dl = (lr == lg * 4 + j);
                    float vd = (cd == 0) ? v0 : (cd == 1) ? v1 : (cd == 2) ? v2 : v3;
                    if (dl) {
                        pos[rf][j] = vd;
                        float nv = -INFINITY;
                        if      (cd == 0) v0 = nv;
                        else if (cd == 1) v1 = nv;
                        else if (cd == 2) v2 = nv;
                        else              v3 = nv;
                    }
                }
                float tmax = fmaxf(fmaxf(v0, v1), fmaxf(v2, v3));
                float nm = fmaxf(mrun[rf][j], tmax);
                float ps = fexp2(v0 - nm) + fexp2(v1 - nm)
                         + fexp2(v2 - nm) + fexp2(v3 - nm);
                lrun[rf][j] = lrun[rf][j] * fexp2(mrun[rf][j] - nm) + ps;
                mrun[rf][j] = nm;
            }
        }
        __syncthreads();   // drains staging vmcnt; next buffer ready
        buf ^= 1;
    }

    float contrib = 0.f;
    #pragma unroll
    for (int rf = 0; rf < 2; ++rf) {
        #pragma unroll
        for (int j = 0; j < 4; ++j) {
            float Mv = mrun[rf][j], Lv = lrun[rf][j];
            #pragma unroll
            for (int s = 1; s < 16; s <<= 1) {
                float Mo = __shfl_xor(Mv, s);
                float Lo = __shfl_xor(Lv, s);
                float nm = fmaxf(Mv, Mo);
                Lv = Lv * fexp2(Mv - nm) + Lo * fexp2(Mo - nm);
                Mv = nm;
            }
            float P = pos[rf][j];
            #pragma unroll
            for (int s = 1; s < 16; s <<= 1) P += __shfl_xor(P, s);
            if (lr == 0) contrib += (Mv + flog2(Lv)) - P;   // log2 domain
        }
    }
    #pragma unroll
    for (int s = 1; s < 64; s <<= 1) contrib += __shfl_xor(contrib, s);

    if (lane == 0) bsum[wave] = contrib;
    __syncthreads();
    if (tid == 0) {
        float t = 0.f;
        #pragma unroll
        for (int w = 0; w < 8; ++w) t += bsum[w];
        atomicAdd(out, t * scale);
    }
}

// ---------------------------------------------------------------------------
extern "C" void kernel_launch(void* const* d_in, const int* in_sizes, int n_in,
                              void* d_out, int out_size, void* d_ws, size_t ws_size,
                              hipStream_t stream) {
    const float* xall = (const float*)d_in[0];
    const float* W    = (const float*)d_in[1];
    const float* b    = (const float*)d_in[2];
    const float* U    = (const float*)d_in[3];
    const float* V    = (const float*)d_in[4];
    float* out = (float*)d_out;

    char* ws = (char*)d_ws;
    __hip_bfloat16* E   = (__hip_bfloat16*)ws;                 // 6.29 MB
    __hip_bfloat16* Whi = E + 2 * (size_t)TOT_ROWS * D_HID;    // 294,912 B
    __hip_bfloat16* Pfhi = Whi + 36 * 8 * 64 * 8;              // 64 KB
    __hip_bfloat16* Pflo = Pfhi + 2 * 32 * 64 * 8;             // 64 KB

    (void)hipMemsetAsync(d_out, 0, sizeof(float), stream);

    prep_kernel<<<352, 64, 0, stream>>>(W, U, V, Whi, Pfhi, Pflo);
    xretrieve_kernel<<<TOT_ROWS / 16, 256, 0, stream>>>(xall, Whi, b, Pfhi, Pflo, E);

    // scale = ln2 (log2 -> ln) / (N rows * 60 pair-jobs)
    const float scale = 0.6931471805599453f / (2048.0f * 60.0f);
    pair_lse_kernel<<<480, 512, 0, stream>>>(E, out, scale);
}